// Round 6
// baseline (58.804 us; speedup 1.0000x reference)
//
#include <hip/hip_runtime.h>
#include <math.h>

#define BATCH 64
#define MEM 1024
#define SENT 16
#define NEMBD 128
#define HID 40
#define HOPS 3
#define NANS 20
#define VOCAB 32000

typedef unsigned int uint;
typedef __attribute__((ext_vector_type(8))) short short8;
typedef __attribute__((ext_vector_type(4))) float f32x4;

__device__ __forceinline__ float blo(uint u){ union{uint i;float f;}c; c.i = u<<16; return c.f; }
__device__ __forceinline__ float bhi(uint u){ union{uint i;float f;}c; c.i = u & 0xffff0000u; return c.f; }
__device__ __forceinline__ unsigned short bfr(float x){
  union{float f;uint i;}c; c.f = x;
  return (unsigned short)((c.i + 0x7fffu + ((c.i>>16)&1u)) >> 16);   // RNE f32->bf16
}
__device__ __forceinline__ uint pkbf(float a, float b){
  union{float f;uint i;}ca, cb; ca.f = a; cb.f = b;
  uint ra = (ca.i + 0x7fffu + ((ca.i>>16)&1u)) >> 16;
  uint rb = (cb.i + 0x7fffu + ((cb.i>>16)&1u)) & 0xffff0000u;
  return rb | ra;
}

// ---- Kernel 0 (MFMA): PQb[v][40] interleaved bf16 pairs (even u = P-pair, odd = Q) ----
__global__ __launch_bounds__(256) void pq_kernel(
    const float* __restrict__ emb, const float* __restrict__ A_w,
    uint* __restrict__ PQb) {
  __shared__ float CmS[64][81];
  const int t = threadIdx.x;
  const int w = t >> 6, l = t & 63;
  const int g = l >> 4, n16 = l & 15;
  const int vbase = blockIdx.x * 64;
  const int row = vbase + w * 16 + n16;

  short8 bfrag[5][4];
#pragma unroll
  for (int nt = 0; nt < 5; ++nt) {
    int pc = nt * 16 + n16;
    int h = 2 * (pc >> 2) + (pc & 1);
    bool isQ = (pc >> 1) & 1;
    const float* wr = A_w + h * NEMBD;
#pragma unroll
    for (int ks = 0; ks < 4; ++ks) {
      int kb = ks * 32 + 8 * g;
      float4 v0 = *reinterpret_cast<const float4*>(wr + kb);
      float4 v1 = *reinterpret_cast<const float4*>(wr + kb + 4);
      float vv[8] = {v0.x, v0.y, v0.z, v0.w, v1.x, v1.y, v1.z, v1.w};
      short8 s;
#pragma unroll
      for (int j = 0; j < 8; ++j) {
        float x = vv[j];
        if (isQ) x *= (float)(kb + j + 1) * (1.0f / 128.0f);
        s[j] = (short)bfr(x);
      }
      bfrag[nt][ks] = s;
    }
  }

  f32x4 acc[5] = {};
  const float* er = emb + (size_t)row * NEMBD;
#pragma unroll
  for (int ks = 0; ks < 4; ++ks) {
    int kb = ks * 32 + 8 * g;
    float4 v0 = *reinterpret_cast<const float4*>(er + kb);
    float4 v1 = *reinterpret_cast<const float4*>(er + kb + 4);
    float vv[8] = {v0.x, v0.y, v0.z, v0.w, v1.x, v1.y, v1.z, v1.w};
    short8 a;
#pragma unroll
    for (int j = 0; j < 8; ++j) a[j] = (short)bfr(vv[j]);
#pragma unroll
    for (int nt = 0; nt < 5; ++nt)
      acc[nt] = __builtin_amdgcn_mfma_f32_16x16x32_bf16(a, bfrag[nt][ks], acc[nt], 0, 0, 0);
  }

#pragma unroll
  for (int nt = 0; nt < 5; ++nt)
#pragma unroll
    for (int r = 0; r < 4; ++r)
      CmS[w * 16 + 4 * g + r][nt * 16 + n16] = acc[nt][r];
  __syncthreads();

#pragma unroll
  for (int it = 0; it < 10; ++it) {
    int i = it * 256 + t;
    int rr = i / 40, u = i % 40;
    PQb[(size_t)(vbase + rr) * 40 + u] = pkbf(CmS[rr][2 * u], CmS[rr][2 * u + 1]);
  }
}

// ---- Kernel A: ekT2[task][hp] = bf16 pair (ek[2hp], ek[2hp+1]); contiguous 80B/task ----
__global__ __launch_bounds__(256) void gather_kernel(
    const int* __restrict__ story, const uint* __restrict__ PQb,
    uint* __restrict__ ekT2) {
  const int t = threadIdx.x;
  const int wid = t >> 6, lane = t & 63;
  const int sub = lane & 31;
  const int tl = wid * 2 + (lane >> 5);        // 0..7
  const int task = blockIdx.x * 8 + tl;        // = b*MEM + m

  int midx = (sub < SENT) ? story[(size_t)task * SENT + sub] : 0;
  const int off = (sub < 20) ? 2 * sub : 0;    // lanes 20-31 dup-load pair 0 (same lines)

  float a0 = 0.f, a1 = 0.f;
#pragma unroll
  for (int s = 0; s < SENT; ++s) {
    int idx = __shfl(midx, (lane & 32) + s);
    uint2 u = *reinterpret_cast<const uint2*>(PQb + (size_t)idx * 40 + off);
    float al = 1.0f - (float)(s + 1) * 0.0625f;
    float be = (float)(s + 1) * 0.125f - 1.0f;
    a0 = fmaf(al, blo(u.x), a0);   // P
    a0 = fmaf(be, blo(u.y), a0);   // Q
    a1 = fmaf(al, bhi(u.x), a1);
    a1 = fmaf(be, bhi(u.y), a1);
  }
  if (sub < 20) ekT2[(size_t)task * 20 + sub] = pkbf(a0, a1);
}

// ---- Kernel B: hops (reg-resident ek scores, b128 o-reduce, 3 barriers/hop) ----
__global__ __launch_bounds__(1024) void hops_kernel(
    const int* __restrict__ story, const int* __restrict__ question,
    const uint* __restrict__ PQb, const uint* __restrict__ ekT2,
    const float* __restrict__ Rs, const float* __restrict__ Wd,
    const float* __restrict__ bd, float* __restrict__ out) {
  __shared__ uint  ekS[1024][20];         // [m][hp] 80 KB; b128 at (80m+16w)B tiles banks
  __shared__ float attnS[1024];
  __shared__ float RsS[HOPS * 40 * 43];   // row stride 43 (coprime*: <=2-way banks)
  __shared__ float WdS[NANS * 41];        // row stride 41
  __shared__ float bdS[NANS];
  __shared__ float qS[2][HID];
  __shared__ float oqS[HID];
  __shared__ float wsum[16];
  __shared__ float lseS;
  __shared__ int   qidxS[SENT];

  const int b = blockIdx.x;
  const int t = threadIdx.x;
  const int wid = t >> 6, lane = t & 63;

  // ---- prologue: per-thread ek column -> regs + LDS mirror ----
  uint ekc[20];
  {
    const uint4* src = reinterpret_cast<const uint4*>(ekT2 + ((size_t)b * 1024 + t) * 20);
    uint4* dst = reinterpret_cast<uint4*>(&ekS[t][0]);
#pragma unroll
    for (int i = 0; i < 5; ++i) {
      uint4 v = src[i];
      ekc[4 * i] = v.x; ekc[4 * i + 1] = v.y; ekc[4 * i + 2] = v.z; ekc[4 * i + 3] = v.w;
      dst[i] = v;
    }
  }
  for (int i = t; i < HOPS * 1600; i += 1024) {
    int hp = i / 1600, rem = i % 1600;
    RsS[hp * 1720 + (rem / 40) * 43 + rem % 40] = Rs[i];
  }
  for (int i = t; i < NANS * 40; i += 1024) WdS[(i / 40) * 41 + i % 40] = Wd[i];
  if (t < NANS) bdS[t] = bd[t];
  if (t < SENT) qidxS[t] = question[b * SENT + t];
  const bool masked = (story[((size_t)b * MEM + t) * SENT] == 0);
  __syncthreads();

  // ---- eq from PQb ----
  if (t < HID) {
    int j = t >> 1, sel = t & 1;
    float acc = 0.f;
    for (int s = 0; s < SENT; ++s) {
      const uint* p = PQb + (size_t)qidxS[s] * 40;
      uint uP = p[2 * j], uQ = p[2 * j + 1];
      float vP = sel ? bhi(uP) : blo(uP);
      float vQ = sel ? bhi(uQ) : blo(uQ);
      float al = 1.0f - (float)(s + 1) * 0.0625f;
      float be = (float)(s + 1) * 0.125f - 1.0f;
      acc = fmaf(al, vP, acc);
      acc = fmaf(be, vQ, acc);
    }
    qS[0][t] = acc;
  }
  __syncthreads();

  int cur = 0;
  for (int hop = 0; hop < HOPS; ++hop) {
    // scores from registers; q via broadcast float2 reads
    float sc = 0.f;
#pragma unroll
    for (int hp = 0; hp < 20; ++hp) {
      float2 qv = *reinterpret_cast<const float2*>(&qS[cur][2 * hp]);
      uint u = ekc[hp];
      sc = fmaf(qv.x, blo(u), sc);
      sc = fmaf(qv.y, bhi(u), sc);
    }
    float ex = masked ? 0.f : __expf(sc);   // |sc| small by construction; no max-sub
    attnS[t] = ex;
    float sm = ex;
#pragma unroll
    for (int off = 32; off; off >>= 1) sm += __shfl_xor(sm, off);
    if (lane == 0) wsum[wid] = sm;
    __syncthreads();                                  // bar A

    if (t < 320) {                                    // 5 waves: wave w owns hp=4w..4w+3
      const int w = wid, c = lane;
      float tot = 0.f;
#pragma unroll
      for (int i = 0; i < 16; ++i) tot += wsum[i];    // broadcast reads
      float inv = 1.0f / tot;
      float o0[4] = {0.f,0.f,0.f,0.f}, o1[4] = {0.f,0.f,0.f,0.f};
#pragma unroll
      for (int j = 0; j < 16; ++j) {
        int m = c + 64 * j;
        float a = attnS[m];
        uint4 u = *reinterpret_cast<const uint4*>(&ekS[m][4 * w]);
        o0[0] = fmaf(a, blo(u.x), o0[0]); o1[0] = fmaf(a, bhi(u.x), o1[0]);
        o0[1] = fmaf(a, blo(u.y), o0[1]); o1[1] = fmaf(a, bhi(u.y), o1[1]);
        o0[2] = fmaf(a, blo(u.z), o0[2]); o1[2] = fmaf(a, bhi(u.z), o1[2]);
        o0[3] = fmaf(a, blo(u.w), o0[3]); o1[3] = fmaf(a, bhi(u.w), o1[3]);
      }
#pragma unroll
      for (int off = 32; off; off >>= 1) {
#pragma unroll
        for (int r = 0; r < 4; ++r) {
          o0[r] += __shfl_xor(o0[r], off);
          o1[r] += __shfl_xor(o1[r], off);
        }
      }
      if (c == 0) {
#pragma unroll
        for (int r = 0; r < 4; ++r) {
          int h = 2 * (4 * w + r);
          oqS[h]     = qS[cur][h]     + inv * o0[r];
          oqS[h + 1] = qS[cur][h + 1] + inv * o1[r];
        }
      }
    }
    __syncthreads();                                  // bar B

    if (t < HID) {                                    // q' = (q+o) @ R^T
      const float* R = &RsS[hop * 1720 + t * 43];
      float acc = 0.f;
#pragma unroll 8
      for (int k = 0; k < HID; ++k) acc = fmaf(oqS[k], R[k], acc);
      qS[cur ^ 1][t] = acc;
    }
    __syncthreads();                                  // bar C
    cur ^= 1;
  }

  // ---- logits + log_softmax ----
  if (t < NANS) {
    float acc = bdS[t];
#pragma unroll 8
    for (int k = 0; k < HID; ++k) acc = fmaf(qS[cur][k], WdS[t * 41 + k], acc);
    attnS[t] = acc;
  }
  __syncthreads();
  if (t == 0) {
    float mx = attnS[0];
    for (int i = 1; i < NANS; ++i) mx = fmaxf(mx, attnS[i]);
    float s2 = 0.f;
    for (int i = 0; i < NANS; ++i) s2 += __expf(attnS[i] - mx);
    lseS = mx + __logf(s2);
  }
  __syncthreads();
  if (t < NANS) out[b * NANS + t] = attnS[t] - lseS;
}

extern "C" void kernel_launch(void* const* d_in, const int* in_sizes, int n_in,
                              void* d_out, int out_size, void* d_ws, size_t ws_size,
                              hipStream_t stream) {
  const int*   story    = (const int*)d_in[0];
  const int*   question = (const int*)d_in[1];
  const float* emb      = (const float*)d_in[3];
  const float* A_w      = (const float*)d_in[4];
  const float* Rs       = (const float*)d_in[6];
  const float* Wd       = (const float*)d_in[7];
  const float* bd       = (const float*)d_in[8];
  float* out = (float*)d_out;

  uint* PQb  = (uint*)d_ws;                       // 32000*40*4 = 5.12 MB
  uint* ekT2 = PQb + (size_t)VOCAB * 40;          // 65536*20*4 = 5.24 MB, 16B-aligned

  pq_kernel<<<VOCAB / 64, 256, 0, stream>>>(emb, A_w, PQb);
  gather_kernel<<<(BATCH * MEM) / 8, 256, 0, stream>>>(story, PQb, ekT2);
  hops_kernel<<<BATCH, 1024, 0, stream>>>(story, question, PQb, ekT2, Rs, Wd, bd, out);
}

// Round 7
// 54.495 us; speedup vs baseline: 1.0791x; 1.0791x over previous
//
#include <hip/hip_runtime.h>
#include <math.h>

#define BATCH 64
#define MEM 1024
#define SENT 16
#define NEMBD 128
#define HID 40
#define HOPS 3
#define NANS 20
#define VOCAB 32000

typedef unsigned int uint;
typedef __attribute__((ext_vector_type(8))) short short8;
typedef __attribute__((ext_vector_type(4))) float f32x4;

__device__ __forceinline__ float blo(uint u){ union{uint i;float f;}c; c.i = u<<16; return c.f; }
__device__ __forceinline__ float bhi(uint u){ union{uint i;float f;}c; c.i = u & 0xffff0000u; return c.f; }
__device__ __forceinline__ unsigned short bfr(float x){
  union{float f;uint i;}c; c.f = x;
  return (unsigned short)((c.i + 0x7fffu + ((c.i>>16)&1u)) >> 16);   // RNE f32->bf16
}
__device__ __forceinline__ uint pkbf(float a, float b){
  union{float f;uint i;}ca, cb; ca.f = a; cb.f = b;
  uint ra = (ca.i + 0x7fffu + ((ca.i>>16)&1u)) >> 16;
  uint rb = (cb.i + 0x7fffu + ((cb.i>>16)&1u)) & 0xffff0000u;
  return rb | ra;
}

// ---- Kernel 0 (MFMA): PQb[v][40] interleaved bf16 pairs (even u = P-pair, odd = Q) ----
// P = emb@A^T, Q = (emb*gamma)@A^T  (pe[s,e] = alpha_s + beta_s*gamma_e is rank-2).
// K-loading uses the same (g,j)->k placement for A and B => dot product is
// correct independent of the HW per-lane k-order (bijection argument).
__global__ __launch_bounds__(256) void pq_kernel(
    const float* __restrict__ emb, const float* __restrict__ A_w,
    uint* __restrict__ PQb) {
  __shared__ float CmS[64][81];
  const int t = threadIdx.x;
  const int w = t >> 6, l = t & 63;
  const int g = l >> 4, n16 = l & 15;
  const int vbase = blockIdx.x * 64;
  const int row = vbase + w * 16 + n16;

  short8 bfrag[5][4];
#pragma unroll
  for (int nt = 0; nt < 5; ++nt) {
    int pc = nt * 16 + n16;
    int h = 2 * (pc >> 2) + (pc & 1);
    bool isQ = (pc >> 1) & 1;
    const float* wr = A_w + h * NEMBD;
#pragma unroll
    for (int ks = 0; ks < 4; ++ks) {
      int kb = ks * 32 + 8 * g;
      float4 v0 = *reinterpret_cast<const float4*>(wr + kb);
      float4 v1 = *reinterpret_cast<const float4*>(wr + kb + 4);
      float vv[8] = {v0.x, v0.y, v0.z, v0.w, v1.x, v1.y, v1.z, v1.w};
      short8 s;
#pragma unroll
      for (int j = 0; j < 8; ++j) {
        float x = vv[j];
        if (isQ) x *= (float)(kb + j + 1) * (1.0f / 128.0f);
        s[j] = (short)bfr(x);
      }
      bfrag[nt][ks] = s;
    }
  }

  f32x4 acc[5] = {};
  const float* er = emb + (size_t)row * NEMBD;
#pragma unroll
  for (int ks = 0; ks < 4; ++ks) {
    int kb = ks * 32 + 8 * g;
    float4 v0 = *reinterpret_cast<const float4*>(er + kb);
    float4 v1 = *reinterpret_cast<const float4*>(er + kb + 4);
    float vv[8] = {v0.x, v0.y, v0.z, v0.w, v1.x, v1.y, v1.z, v1.w};
    short8 a;
#pragma unroll
    for (int j = 0; j < 8; ++j) a[j] = (short)bfr(vv[j]);
#pragma unroll
    for (int nt = 0; nt < 5; ++nt)
      acc[nt] = __builtin_amdgcn_mfma_f32_16x16x32_bf16(a, bfrag[nt][ks], acc[nt], 0, 0, 0);
  }

  // C/D layout (verified): lane l reg r -> row 4*(l>>4)+r, col l&15
#pragma unroll
  for (int nt = 0; nt < 5; ++nt)
#pragma unroll
    for (int r = 0; r < 4; ++r)
      CmS[w * 16 + 4 * g + r][nt * 16 + n16] = acc[nt][r];
  __syncthreads();

#pragma unroll
  for (int it = 0; it < 10; ++it) {
    int i = it * 256 + t;
    int rr = i / 40, u = i % 40;
    PQb[(size_t)(vbase + rr) * 40 + u] = pkbf(CmS[rr][2 * u], CmS[rr][2 * u + 1]);
  }
}

// ---- Kernel A: ekT2[b][hp][m] = bf16 pair (ek[2hp], ek[2hp+1]); no LDS, no sync ----
__global__ __launch_bounds__(256) void gather_kernel(
    const int* __restrict__ story, const uint* __restrict__ PQb,
    uint* __restrict__ ekT2) {
  const int t = threadIdx.x;
  const int wid = t >> 6, lane = t & 63;
  const int sub = lane & 31;
  const int tl = wid * 2 + (lane >> 5);        // 0..7
  const int task = blockIdx.x * 8 + tl;        // = b*MEM + m

  int midx = (sub < SENT) ? story[(size_t)task * SENT + sub] : 0;
  const int off = (sub < 20) ? 2 * sub : 0;    // lanes 20-31 dup-load pair 0 (same lines)

  float a0 = 0.f, a1 = 0.f;
#pragma unroll
  for (int s = 0; s < SENT; ++s) {
    int idx = __shfl(midx, (lane & 32) + s);
    uint2 u = *reinterpret_cast<const uint2*>(PQb + (size_t)idx * 40 + off);
    float al = 1.0f - (float)(s + 1) * 0.0625f;
    float be = (float)(s + 1) * 0.125f - 1.0f;
    a0 = fmaf(al, blo(u.x), a0);   // P
    a0 = fmaf(be, blo(u.y), a0);   // Q
    a1 = fmaf(al, bhi(u.x), a1);
    a1 = fmaf(be, bhi(u.y), a1);
  }
  if (sub < 20) {
    int b = task >> 10, m = task & 1023;
    ekT2[((size_t)b * 20 + sub) * 1024 + m] = pkbf(a0, a1);
  }
}

// ---- Kernel B: hops + logits + log_softmax (ekT in LDS, shuffle-free o-reduce) ----
__global__ __launch_bounds__(1024) void hops_kernel(
    const int* __restrict__ story, const int* __restrict__ question,
    const uint* __restrict__ PQb, const uint* __restrict__ ekT2,
    const float* __restrict__ Rs, const float* __restrict__ Wd,
    const float* __restrict__ bd, float* __restrict__ out) {
  __shared__ uint  ekS[20][1024];         // 80 KB bf16 pairs
  __shared__ float attnS[1024];           // raw exp(sc)
  __shared__ float wpart[32][42];
  __shared__ float RsS[HOPS * HID * HID];
  __shared__ float WdS[NANS * HID];
  __shared__ float bdS[NANS];
  __shared__ float qS[2][HID];
  __shared__ float oqS[HID];
  __shared__ float wsum[16];
  __shared__ float invS;
  __shared__ float lseS;
  __shared__ int   qidxS[SENT];

  const int b = blockIdx.x;
  const int t = threadIdx.x;
  const int wid = t >> 6, lane = t & 63;

  {
    const uint* src = ekT2 + (size_t)b * 20 * 1024;
#pragma unroll
    for (int j = 0; j < 5; ++j) {
      uint4 v = reinterpret_cast<const uint4*>(src)[j * 1024 + t];
      *reinterpret_cast<uint4*>(&ekS[0][0] + 4 * (j * 1024 + t)) = v;
    }
  }
  for (int i = t; i < HOPS * HID * HID; i += 1024) RsS[i] = Rs[i];
  for (int i = t; i < NANS * HID; i += 1024) WdS[i] = Wd[i];
  if (t < NANS) bdS[t] = bd[t];
  if (t < SENT) qidxS[t] = question[b * SENT + t];
  const bool masked = (story[((size_t)b * MEM + t) * SENT] == 0);
  __syncthreads();

  // ---- eq from PQb (interleaved layout) ----
  if (t < HID) {
    int j = t >> 1, sel = t & 1;
    float acc = 0.f;
    for (int s = 0; s < SENT; ++s) {
      const uint* p = PQb + (size_t)qidxS[s] * 40;
      uint uP = p[2 * j], uQ = p[2 * j + 1];
      float vP = sel ? bhi(uP) : blo(uP);
      float vQ = sel ? bhi(uQ) : blo(uQ);
      float al = 1.0f - (float)(s + 1) * 0.0625f;
      float be = (float)(s + 1) * 0.125f - 1.0f;
      acc = fmaf(al, vP, acc);
      acc = fmaf(be, vQ, acc);
    }
    qS[0][t] = acc;
  }
  __syncthreads();

  int cur = 0;
  for (int hop = 0; hop < HOPS; ++hop) {
    float sc = 0.f;
#pragma unroll
    for (int hp = 0; hp < 20; ++hp) {
      uint u = ekS[hp][t];
      sc = fmaf(qS[cur][2 * hp],     blo(u), sc);
      sc = fmaf(qS[cur][2 * hp + 1], bhi(u), sc);
    }
    float ex = masked ? 0.f : __expf(sc);   // |sc| small by construction; no max-sub
    attnS[t] = ex;
    float sm = ex;
#pragma unroll
    for (int off = 32; off; off >>= 1) sm += __shfl_xor(sm, off);
    if (lane == 0) wsum[wid] = sm;
    __syncthreads();                                  // bar A

    if (t < 640) {                                    // o partials, LDS-transpose
      int hp = t >> 5, c = t & 31;
      float o0 = 0.f, o1 = 0.f;
#pragma unroll 8
      for (int j = 0; j < 32; ++j) {
        int m = c + (j << 5);                         // conflict-free: bank = c
        float a = attnS[m];
        uint u = ekS[hp][m];
        o0 = fmaf(a, blo(u), o0);
        o1 = fmaf(a, bhi(u), o1);
      }
      wpart[c][2 * hp]     = o0;
      wpart[c][2 * hp + 1] = o1;
    } else if (t == 1023) {
      float tot = 0.f;
#pragma unroll
      for (int i = 0; i < 16; ++i) tot += wsum[i];
      invS = 1.0f / tot;
    }
    __syncthreads();                                  // bar B

    if (t < HID) {
      float s2 = 0.f;
#pragma unroll 8
      for (int c = 0; c < 32; ++c) s2 += wpart[c][t];
      oqS[t] = qS[cur][t] + invS * s2;
    }
    __syncthreads();                                  // bar C

    if (t < HID) {
      const float* R = &RsS[hop * HID * HID + t * HID];
      float acc = 0.f;
#pragma unroll 8
      for (int k = 0; k < HID; ++k) acc = fmaf(oqS[k], R[k], acc);
      qS[cur ^ 1][t] = acc;
    }
    __syncthreads();                                  // bar D
    cur ^= 1;
  }

  if (t < NANS) {
    float acc = bdS[t];
#pragma unroll 8
    for (int k = 0; k < HID; ++k) acc = fmaf(qS[cur][k], WdS[t * HID + k], acc);
    attnS[t] = acc;
  }
  __syncthreads();
  if (t == 0) {
    float mx = attnS[0];
    for (int i = 1; i < NANS; ++i) mx = fmaxf(mx, attnS[i]);
    float s2 = 0.f;
    for (int i = 0; i < NANS; ++i) s2 += __expf(attnS[i] - mx);
    lseS = mx + __logf(s2);
  }
  __syncthreads();
  if (t < NANS) out[b * NANS + t] = attnS[t] - lseS;
}

extern "C" void kernel_launch(void* const* d_in, const int* in_sizes, int n_in,
                              void* d_out, int out_size, void* d_ws, size_t ws_size,
                              hipStream_t stream) {
  const int*   story    = (const int*)d_in[0];
  const int*   question = (const int*)d_in[1];
  const float* emb      = (const float*)d_in[3];
  const float* A_w      = (const float*)d_in[4];
  const float* Rs       = (const float*)d_in[6];
  const float* Wd       = (const float*)d_in[7];
  const float* bd       = (const float*)d_in[8];
  float* out = (float*)d_out;

  uint* PQb  = (uint*)d_ws;                       // 32000*40*4 = 5.12 MB
  uint* ekT2 = PQb + (size_t)VOCAB * 40;          // 64*20*1024*4 = 5.24 MB

  pq_kernel<<<VOCAB / 64, 256, 0, stream>>>(emb, A_w, PQb);
  gather_kernel<<<(BATCH * MEM) / 8, 256, 0, stream>>>(story, PQb, ekT2);
  hops_kernel<<<BATCH, 1024, 0, stream>>>(story, question, PQb, ekT2, Rs, Wd, bd, out);
}